// Round 1
// baseline (196.939 us; speedup 1.0000x reference)
//
#include <hip/hip_runtime.h>

namespace {
constexpr int Hh = 64, Wd = 64, Cc = 256, RED = 64, EE = 144;
constexpr int TPX = 32;          // pixels per block (half a row)
constexpr int XS_STRIDE = 260;   // padded stride for x tile (floats)
constexpr int EW_STRIDE = 145;   // padded stride for e weights

__global__ __launch_bounds__(256) void invo_fused(
    const float* __restrict__ x,
    const float* __restrict__ W1,
    const float* __restrict__ b1,
    const float* __restrict__ W2,
    const float* __restrict__ b2,
    float* __restrict__ out)
{
  __shared__ float xs[TPX * XS_STRIDE];   // 33,280 B; reused as ew[TPX*EW_STRIDE]
  __shared__ float smid[RED * TPX];       // 8,192 B  mid[d][p]

  const int t = threadIdx.x;
  const int blk = blockIdx.x;          // (b*64 + h)*2 + half
  const int half = blk & 1;
  const int bh = blk >> 1;
  const int h = bh & 63;
  const int b = bh >> 6;
  const int w0 = half * TPX;
  const int pixbase = (b * Hh + h) * Wd + w0;
  const float* xtile = x + (size_t)pixbase * Cc;

  // ---- stage x tile into LDS (pixel-major, padded) ----
#pragma unroll
  for (int j = 0; j < 8; ++j) {
    int i = (j * 256 + t) * 4;           // 0..8188 step 4, unique per (j,t)
    int p = i >> 8;
    int c = i & 255;
    float4 v = *(const float4*)(xtile + p * Cc + c);
    *(float4*)(xs + p * XS_STRIDE + c) = v;
  }
  __syncthreads();

  // ---- GEMM1: mid[d][p] = b1[d] + sum_c x[p][c] * W1[c][d] ----
  {
    const int pg = t & 15, dg = t >> 4;
    const int p0 = pg * 2, d0 = dg * 4;
    float acc[2][4] = {};
    for (int c = 0; c < Cc; c += 4) {
      float a[2][4];
#pragma unroll
      for (int i = 0; i < 2; ++i) {
        float4 v = *(const float4*)(xs + (p0 + i) * XS_STRIDE + c);
        a[i][0] = v.x; a[i][1] = v.y; a[i][2] = v.z; a[i][3] = v.w;
      }
      float wv[4][4];
#pragma unroll
      for (int kk = 0; kk < 4; ++kk) {
        float4 v = *(const float4*)(W1 + (c + kk) * RED + d0);
        wv[kk][0] = v.x; wv[kk][1] = v.y; wv[kk][2] = v.z; wv[kk][3] = v.w;
      }
#pragma unroll
      for (int kk = 0; kk < 4; ++kk)
#pragma unroll
        for (int i = 0; i < 2; ++i)
#pragma unroll
          for (int jj = 0; jj < 4; ++jj)
            acc[i][jj] += a[i][kk] * wv[kk][jj];
    }
#pragma unroll
    for (int jj = 0; jj < 4; ++jj)
#pragma unroll
      for (int i = 0; i < 2; ++i)
        smid[(d0 + jj) * TPX + (p0 + i)] = acc[i][jj] + b1[d0 + jj];
  }
  __syncthreads();

  // ---- GEMM2: ew[p][e] = b2[e] + sum_c mid[c][p] * W2[c][e] ----
  float* ew = xs;  // xs dead after GEMM1; reuse the LDS
  {
    const int pg = t & 15, eg = t >> 4;
    const int p0 = pg * 2, e0 = eg * 9;
    float acc[2][9] = {};
    for (int c = 0; c < RED; ++c) {
      float2 m = *(const float2*)(smid + c * TPX + p0);
      const float* wrow = W2 + c * EE + e0;
#pragma unroll
      for (int jj = 0; jj < 9; ++jj) {
        float wv = wrow[jj];
        acc[0][jj] += m.x * wv;
        acc[1][jj] += m.y * wv;
      }
    }
#pragma unroll
    for (int i = 0; i < 2; ++i)
#pragma unroll
      for (int jj = 0; jj < 9; ++jj)
        ew[(p0 + i) * EW_STRIDE + e0 + jj] = acc[i][jj] + b2[e0 + jj];
  }
  __syncthreads();

  // ---- involution: out[p][co] = sum_k ew[p][g*9+k] * x_patch(f=g*144+gc*9+k) ----
  {
    const int co = t;
    const int g = co >> 4, gc = co & 15;
    const int f0 = g * 144 + gc * 9;
    const int wi0 = g * 9;
    int ch[9], rbase[9], dj[9], rvalid[9];
#pragma unroll
    for (int k = 0; k < 9; ++k) {
      int fv = f0 + k;
      ch[k] = fv & 255;
      int ks = fv >> 8;          // which 3x3 tap (0..8)
      int di = ks / 3;
      int djj = ks - di * 3;
      int hh = h + di - 1;
      rvalid[k] = ((unsigned)hh < (unsigned)Hh) ? 1 : 0;
      rbase[k] = ((b * Hh + hh) * Wd) * Cc + ch[k];
      dj[k] = djj - 1;
    }
    for (int p = 0; p < TPX; ++p) {
      float acc = 0.f;
      const float* ewp = ew + p * EW_STRIDE + wi0;
#pragma unroll
      for (int k = 0; k < 9; ++k) {
        int ww = w0 + p + dj[k];
        float xv = 0.f;
        if (rvalid[k] && (unsigned)ww < (unsigned)Wd)
          xv = x[rbase[k] + ww * Cc];
        acc += ewp[k] * xv;
      }
      out[(size_t)(pixbase + p) * Cc + co] = acc;
    }
  }
}
} // namespace

extern "C" void kernel_launch(void* const* d_in, const int* in_sizes, int n_in,
                              void* d_out, int out_size, void* d_ws, size_t ws_size,
                              hipStream_t stream) {
  const float* x  = (const float*)d_in[0];
  const float* W1 = (const float*)d_in[1];
  const float* b1 = (const float*)d_in[2];
  const float* W2 = (const float*)d_in[3];
  const float* b2 = (const float*)d_in[4];
  float* out = (float*)d_out;
  dim3 grid(8 * 64 * 2);   // b * h * (W/TPX)
  invo_fused<<<grid, 256, 0, stream>>>(x, W1, b1, W2, b2, out);
}

// Round 2
// 178.674 us; speedup vs baseline: 1.1022x; 1.1022x over previous
//
#include <hip/hip_runtime.h>

namespace {
constexpr int XP = 264;        // xg pixel pitch (bf16 elems): 528B -> bank stride 4, conflict-free-ish
constexpr int XR = 18 * XP;    // xg row pitch
constexpr int MP = 20;         // smid pitch (floats): 80B -> float4-aligned rows
constexpr int EP = 146;        // ew pixel pitch (bf16 elems)

__device__ __forceinline__ unsigned short f2bf(float f) {
  unsigned u = __builtin_bit_cast(unsigned, f);
  u += 0x7fffu + ((u >> 16) & 1u);         // RNE
  return (unsigned short)(u >> 16);
}
__device__ __forceinline__ float bf2f(unsigned short s) {
  unsigned u = ((unsigned)s) << 16;
  return __builtin_bit_cast(float, u);
}

__global__ __launch_bounds__(256) void invo_fused(
    const float* __restrict__ x, const float* __restrict__ W1,
    const float* __restrict__ b1, const float* __restrict__ W2,
    const float* __restrict__ b2, float* __restrict__ out)
{
  __shared__ unsigned short xg[3 * XR];     // 28,512 B  bf16 halo patch [row][px][ch]
  __shared__ float smid[64 * MP];           //  5,120 B  mid[d][p] fp32
  __shared__ unsigned short ew[16 * EP];    //  4,672 B  e-weights bf16 [p][144]
                                            // total 38,304 B -> 4 blocks/CU

  const int t = threadIdx.x;
  const int blk = blockIdx.x;               // (b*64 + h)*4 + strip
  const int strip = blk & 3;
  const int bh = blk >> 2;
  const int h = bh & 63;
  const int b = bh >> 6;
  const int w0 = strip * 16;

  // ---- stage 3 halo rows x 18 px x 256 ch, fp32 -> bf16, zero-fill OOB ----
  for (int idx = t; idx < 3 * 18 * 64; idx += 256) {
    int c4 = (idx & 63) << 2;
    int pr = idx >> 6;                      // 0..53
    int r = (pr >= 36) ? 2 : (pr >= 18 ? 1 : 0);
    int j = pr - r * 18;
    int hh = h + r - 1, ww = w0 + j - 1;
    float4 v = make_float4(0.f, 0.f, 0.f, 0.f);
    if (((unsigned)hh < 64u) && ((unsigned)ww < 64u))
      v = *(const float4*)(x + ((((b << 6) + hh) << 6) + ww) * 256 + c4);
    ushort4 s;
    s.x = f2bf(v.x); s.y = f2bf(v.y); s.z = f2bf(v.z); s.w = f2bf(v.w);
    *(ushort4*)(&xg[r * XR + j * XP + c4]) = s;
  }
  __syncthreads();

  // ---- GEMM1: mid[p][d] = b1[d] + sum_c x[p][c]*W1[c][d]; store transposed fp32 ----
  {
    const int p = t & 15, d0 = (t >> 4) << 2;
    float a0 = 0.f, a1 = 0.f, a2 = 0.f, a3 = 0.f;
    const unsigned short* xrow = &xg[XR + (p + 1) * XP];
    for (int c = 0; c < 256; c += 4) {
      ushort4 s = *(const ushort4*)(xrow + c);
      float x0 = bf2f(s.x), x1 = bf2f(s.y), x2 = bf2f(s.z), x3 = bf2f(s.w);
      float4 w0v = *(const float4*)(W1 + (c + 0) * 64 + d0);
      float4 w1v = *(const float4*)(W1 + (c + 1) * 64 + d0);
      float4 w2v = *(const float4*)(W1 + (c + 2) * 64 + d0);
      float4 w3v = *(const float4*)(W1 + (c + 3) * 64 + d0);
      a0 += x0 * w0v.x + x1 * w1v.x + x2 * w2v.x + x3 * w3v.x;
      a1 += x0 * w0v.y + x1 * w1v.y + x2 * w2v.y + x3 * w3v.y;
      a2 += x0 * w0v.z + x1 * w1v.z + x2 * w2v.z + x3 * w3v.z;
      a3 += x0 * w0v.w + x1 * w1v.w + x2 * w2v.w + x3 * w3v.w;
    }
    smid[(d0 + 0) * MP + p] = a0 + b1[d0 + 0];
    smid[(d0 + 1) * MP + p] = a1 + b1[d0 + 1];
    smid[(d0 + 2) * MP + p] = a2 + b1[d0 + 2];
    smid[(d0 + 3) * MP + p] = a3 + b1[d0 + 3];
  }
  __syncthreads();

  // ---- GEMM2: thread=e (<144): e[p][e] = b2[e] + sum_d mid[d][p]*W2[d][e] ----
  if (t < 144) {
    float acc[16];
#pragma unroll
    for (int p = 0; p < 16; ++p) acc[p] = 0.f;
    for (int d = 0; d < 64; ++d) {
      float wv = W2[d * 144 + t];           // lanes e-consecutive: coalesced
      const float4* mr = (const float4*)&smid[d * MP];  // broadcast reads
      float4 m0 = mr[0], m1 = mr[1], m2 = mr[2], m3 = mr[3];
      acc[0]  += m0.x * wv; acc[1]  += m0.y * wv; acc[2]  += m0.z * wv; acc[3]  += m0.w * wv;
      acc[4]  += m1.x * wv; acc[5]  += m1.y * wv; acc[6]  += m1.z * wv; acc[7]  += m1.w * wv;
      acc[8]  += m2.x * wv; acc[9]  += m2.y * wv; acc[10] += m2.z * wv; acc[11] += m2.w * wv;
      acc[12] += m3.x * wv; acc[13] += m3.y * wv; acc[14] += m3.z * wv; acc[15] += m3.w * wv;
    }
    float bb = b2[t];
#pragma unroll
    for (int p = 0; p < 16; ++p) ew[p * EP + t] = f2bf(acc[p] + bb);
  }
  __syncthreads();

  // ---- involution: thread=(p,g); out[p][g*16+gc] = sum_k e[p][g*9+k]*xg[tap(f)][ch(f)],
  //      f = (g*16+gc)*9 + k = g*144 + gc*9 + k ----
  {
    const int p = t >> 4, g = t & 15;
    float ewr[9];
#pragma unroll
    for (int k = 0; k < 9; ++k) ewr[k] = bf2f(ew[p * EP + g * 9 + k]);
    const int g144 = g * 144;
    const int pbase = p * XP;
    float res[16];
#pragma unroll
    for (int gc = 0; gc < 16; ++gc) {
      float acc = 0.f;
#pragma unroll
      for (int k = 0; k < 9; ++k) {
        int f = g144 + gc * 9 + k;
        int ch = f & 255;
        int ks = f >> 8;                    // tap 0..8
        int di = (ks * 86) >> 8;            // ks/3
        int off = XP * (ks + 15 * di) + ch; // di*XR + (ks-3di)*XP + ch
        acc += ewr[k] * bf2f(xg[pbase + off]);
      }
      res[gc] = acc;
    }
    float* orow = out + (size_t)(((((b << 6) + h) << 6) + w0 + p)) * 256 + (g << 4);
    *(float4*)(orow + 0)  = make_float4(res[0],  res[1],  res[2],  res[3]);
    *(float4*)(orow + 4)  = make_float4(res[4],  res[5],  res[6],  res[7]);
    *(float4*)(orow + 8)  = make_float4(res[8],  res[9],  res[10], res[11]);
    *(float4*)(orow + 12) = make_float4(res[12], res[13], res[14], res[15]);
  }
}
} // namespace

extern "C" void kernel_launch(void* const* d_in, const int* in_sizes, int n_in,
                              void* d_out, int out_size, void* d_ws, size_t ws_size,
                              hipStream_t stream) {
  const float* x  = (const float*)d_in[0];
  const float* W1 = (const float*)d_in[1];
  const float* b1 = (const float*)d_in[2];
  const float* W2 = (const float*)d_in[3];
  const float* b2 = (const float*)d_in[4];
  float* out = (float*)d_out;
  dim3 grid(8 * 64 * 4);   // b * h * (W/16)
  invo_fused<<<grid, 256, 0, stream>>>(x, W1, b1, W2, b2, out);
}

// Round 3
// 118.909 us; speedup vs baseline: 1.6562x; 1.5026x over previous
//
#include <hip/hip_runtime.h>

namespace {
constexpr int XP = 264;        // xg pixel pitch (bf16 elems), 16B-aligned (33 chunks)
constexpr int XR = 18 * XP;    // xg row pitch
constexpr int EWP = 148;       // ew pixel pitch (floats)

typedef __bf16 bf16x8 __attribute__((ext_vector_type(8)));
typedef float f32x4 __attribute__((ext_vector_type(4)));
typedef unsigned short us8 __attribute__((ext_vector_type(8)));

__device__ __forceinline__ unsigned short f2bf(float f) {
  unsigned u = __builtin_bit_cast(unsigned, f);
  u += 0x7fffu + ((u >> 16) & 1u);         // RNE
  return (unsigned short)(u >> 16);
}
__device__ __forceinline__ float bf2f(unsigned short s) {
  unsigned u = ((unsigned)s) << 16;
  return __builtin_bit_cast(float, u);
}

// ---- prep: W12 = W1*W2 packed in B-frag order (bf16), b12 = b1*W2 + b2 ----
__global__ __launch_bounds__(256) void prep_w12(
    const float* __restrict__ W1, const float* __restrict__ b1,
    const float* __restrict__ W2, const float* __restrict__ b2,
    unsigned short* __restrict__ pack, float* __restrict__ b12)
{
  __shared__ float sW1[256 * 66];          // pitch 66: float2-aligned, 4-way-read worst case
  const int t = threadIdx.x, e = blockIdx.x;
#pragma unroll
  for (int j = 0; j < 32; ++j) {
    int idx = (j * 256 + t) * 2;           // 0..16382
    int c = idx >> 6, d = idx & 63;
    float2 v = *(const float2*)(W1 + idx);
    *(float2*)(&sW1[c * 66 + d]) = v;
  }
  __syncthreads();
  const int c = t;
  float acc = 0.f;
  for (int d = 0; d < 64; ++d)
    acc += sW1[c * 66 + d] * W2[d * 144 + e];
  // pack[((T*8+s)*64 + q*16 + n)*8 + j], c = s*32+q*8+j, e = T*16+n
  int T = e >> 4, n = e & 15;
  int s = c >> 5, q = (c >> 3) & 3, j = c & 7;
  pack[(((T * 8 + s) * 64 + q * 16 + n) << 3) + j] = f2bf(acc);
  if (t == 0) {
    float bb = b2[e];
    for (int d = 0; d < 64; ++d) bb += b1[d] * W2[d * 144 + e];
    b12[e] = bb;
  }
}

// ---- main: halo stage -> MFMA GEMM (e = x*W12+b12) -> vectorized involution ----
__global__ __launch_bounds__(256) void invo_fused(
    const float* __restrict__ x,
    const unsigned short* __restrict__ pack,
    const float* __restrict__ b12g,
    float* __restrict__ out)
{
  __shared__ __align__(16) unsigned short xg[3 * XR];  // 28,512 B bf16 halo [row][px][ch]
  __shared__ float ew[16 * EWP];                       //  9,472 B fp32 e-weights [p][144]

  const int t = threadIdx.x;
  const int blk = blockIdx.x;               // (b*64 + h)*4 + strip
  const int strip = blk & 3;
  const int bh = blk >> 2;
  const int h = bh & 63;
  const int b = bh >> 6;
  const int w0 = strip * 16;

  // ---- stage 3 halo rows x 18 px x 256 ch, fp32 -> bf16, zero-fill OOB ----
  for (int idx = t; idx < 3 * 18 * 64; idx += 256) {
    int c4 = (idx & 63) << 2;
    int pr = idx >> 6;                      // 0..53
    int r = (pr >= 36) ? 2 : (pr >= 18 ? 1 : 0);
    int j = pr - r * 18;
    int hh = h + r - 1, ww = w0 + j - 1;
    float4 v = make_float4(0.f, 0.f, 0.f, 0.f);
    if (((unsigned)hh < 64u) && ((unsigned)ww < 64u))
      v = *(const float4*)(x + ((((b << 6) + hh) << 6) + ww) * 256 + c4);
    ushort4 s;
    s.x = f2bf(v.x); s.y = f2bf(v.y); s.z = f2bf(v.z); s.w = f2bf(v.w);
    *(ushort4*)(&xg[r * XR + j * XP + c4]) = s;
  }
  __syncthreads();

  // ---- GEMM via MFMA: e[p][e] = b12[e] + sum_c x[p][c] * W12[c][e] ----
  {
    const int wave = t >> 6, lane = t & 63;
    const int q = lane >> 4, m = lane & 15;   // m = pixel row of A, also n = col of B/D
    bf16x8 A[8];
    const unsigned short* arow = &xg[XR + (m + 1) * XP + q * 8];
#pragma unroll
    for (int s = 0; s < 8; ++s)
      A[s] = __builtin_bit_cast(bf16x8, *(const us8*)(arow + s * 32));
    for (int T = wave; T < 9; T += 4) {
      f32x4 acc = {0.f, 0.f, 0.f, 0.f};
      const us8* bp = (const us8*)pack + (T * 8) * 64 + lane;
#pragma unroll
      for (int s = 0; s < 8; ++s) {
        bf16x8 B = __builtin_bit_cast(bf16x8, bp[s * 64]);
        acc = __builtin_amdgcn_mfma_f32_16x16x32_bf16(A[s], B, acc, 0, 0, 0);
      }
      float bb = b12g[T * 16 + m];            // col n == m bits
#pragma unroll
      for (int r = 0; r < 4; ++r)
        ew[(q * 4 + r) * EWP + T * 16 + m] = acc[r] + bb;   // D row = q*4+r, col = n
    }
  }
  __syncthreads();

  // ---- involution: thread=(p,g); 18x ds_read_b128 over contiguous f-chunks ----
  {
    const int p = t >> 4, g = t & 15;
    float ewr[9];
#pragma unroll
    for (int k = 0; k < 9; ++k) ewr[k] = ew[p * EWP + g * 9 + k];
    const int g144 = g * 144;
    float res[16];
#pragma unroll
    for (int gc = 0; gc < 16; ++gc) res[gc] = 0.f;
#pragma unroll
    for (int j = 0; j < 18; ++j) {
      int f = g144 + j * 8;
      int tap = f >> 8;                     // constant within the 8-chunk
      int ch = f & 255;
      int di = (tap * 86) >> 8;             // tap/3
      int dj = tap - 3 * di;
      us8 v = *(const us8*)(&xg[di * XR + (p + dj) * XP + ch]);
#pragma unroll
      for (int i = 0; i < 8; ++i) {
        int u = j * 8 + i;                  // compile-time per (j,i)
        res[u / 9] += ewr[u % 9] * bf2f((unsigned short)v[i]);
      }
    }
    float* orow = out + (size_t)(((((b << 6) + h) << 6) + w0 + p)) * 256 + (g << 4);
    *(float4*)(orow + 0)  = make_float4(res[0],  res[1],  res[2],  res[3]);
    *(float4*)(orow + 4)  = make_float4(res[4],  res[5],  res[6],  res[7]);
    *(float4*)(orow + 8)  = make_float4(res[8],  res[9],  res[10], res[11]);
    *(float4*)(orow + 12) = make_float4(res[12], res[13], res[14], res[15]);
  }
}
} // namespace

extern "C" void kernel_launch(void* const* d_in, const int* in_sizes, int n_in,
                              void* d_out, int out_size, void* d_ws, size_t ws_size,
                              hipStream_t stream) {
  const float* x  = (const float*)d_in[0];
  const float* W1 = (const float*)d_in[1];
  const float* b1 = (const float*)d_in[2];
  const float* W2 = (const float*)d_in[3];
  const float* b2 = (const float*)d_in[4];
  float* out = (float*)d_out;
  unsigned short* pack = (unsigned short*)d_ws;           // 9*8*64*8 u16 = 73,728 B
  float* b12 = (float*)((char*)d_ws + 9 * 8 * 64 * 8 * 2);
  prep_w12<<<144, 256, 0, stream>>>(W1, b1, W2, b2, pack, b12);
  invo_fused<<<8 * 64 * 4, 256, 0, stream>>>(x, pack, b12, out);
}

// Round 5
// 117.940 us; speedup vs baseline: 1.6698x; 1.0082x over previous
//
#include <hip/hip_runtime.h>

namespace {
constexpr int XP = 264;        // xg pixel pitch (f16 elems)
constexpr int XR = 18 * XP;    // xg row pitch
constexpr int EWP = 148;       // ew pixel pitch (floats)

typedef _Float16 h2 __attribute__((ext_vector_type(2)));
typedef _Float16 h8 __attribute__((ext_vector_type(8)));
typedef float f32x4 __attribute__((ext_vector_type(4)));

__device__ __forceinline__ h2 pkrtz(float a, float b) {
  return __builtin_bit_cast(h2, __builtin_amdgcn_cvt_pkrtz(a, b));
}

#if __has_builtin(__builtin_amdgcn_fdot2)
#define HAS_FDOT2 1
#else
#define HAS_FDOT2 0
#endif

// ---- prep: W12 = W1*W2 packed in f16 B-frag order, b12 = b1*W2 + b2 ----
__global__ __launch_bounds__(256) void prep_w12(
    const float* __restrict__ W1, const float* __restrict__ b1,
    const float* __restrict__ W2, const float* __restrict__ b2,
    _Float16* __restrict__ pack, float* __restrict__ b12)
{
  __shared__ float sW1[256 * 66];
  const int t = threadIdx.x, e = blockIdx.x;
#pragma unroll
  for (int j = 0; j < 32; ++j) {
    int idx = (j * 256 + t) * 2;
    int c = idx >> 6, d = idx & 63;
    float2 v = *(const float2*)(W1 + idx);
    *(float2*)(&sW1[c * 66 + d]) = v;
  }
  __syncthreads();
  const int c = t;
  float acc = 0.f;
  for (int d = 0; d < 64; ++d)
    acc += sW1[c * 66 + d] * W2[d * 144 + e];
  // pack[((T*8+s)*64 + q*16 + n)*8 + j], c = s*32+q*8+j, e = T*16+n
  int T = e >> 4, n = e & 15;
  int s = c >> 5, q = (c >> 3) & 3, j = c & 7;
  pack[(((T * 8 + s) * 64 + q * 16 + n) << 3) + j] = (_Float16)acc;
  if (t == 0) {
    float bb = b2[e];
    for (int d = 0; d < 64; ++d) bb += b1[d] * W2[d * 144 + e];
    b12[e] = bb;
  }
}

// ---- main: f16 halo stage -> f16 MFMA GEMM -> dot2 involution ----
__global__ __launch_bounds__(256) void invo_fused(
    const float* __restrict__ x,
    const _Float16* __restrict__ pack,
    const float* __restrict__ b12g,
    float* __restrict__ out)
{
  __shared__ __align__(16) _Float16 xg[3 * XR];   // 28,512 B f16 halo [row][px][ch]
  __shared__ float ew[16 * EWP];                  //  9,472 B fp32 e-weights [p][144]

  const int t = threadIdx.x;
  const int blk = blockIdx.x;               // (b*64 + h)*4 + strip
  const int strip = blk & 3;
  const int bh = blk >> 2;
  const int h = bh & 63;
  const int b = bh >> 6;
  const int w0 = strip * 16;

  // ---- stage 3 halo rows x 18 px x 256 ch, fp32 -> f16 (packed cvt), zero OOB ----
  for (int idx = t; idx < 3 * 18 * 64; idx += 256) {
    int c4 = (idx & 63) << 2;
    int pr = idx >> 6;                      // 0..53
    int r = (pr >= 36) ? 2 : (pr >= 18 ? 1 : 0);
    int j = pr - r * 18;
    int hh = h + r - 1, ww = w0 + j - 1;
    float4 v = make_float4(0.f, 0.f, 0.f, 0.f);
    if (((unsigned)hh < 64u) && ((unsigned)ww < 64u))
      v = *(const float4*)(x + ((((b << 6) + hh) << 6) + ww) * 256 + c4);
    h2 lo = pkrtz(v.x, v.y);
    h2 hi = pkrtz(v.z, v.w);
    uint2 u;
    u.x = __builtin_bit_cast(unsigned, lo);
    u.y = __builtin_bit_cast(unsigned, hi);
    *(uint2*)(&xg[r * XR + j * XP + c4]) = u;
  }
  __syncthreads();

  // ---- GEMM via MFMA: e[p][e] = b12[e] + sum_c x[p][c] * W12[c][e] ----
  {
    const int wave = t >> 6, lane = t & 63;
    const int q = lane >> 4, m = lane & 15;
    h8 A[8];
    const _Float16* arow = &xg[XR + (m + 1) * XP + q * 8];
#pragma unroll
    for (int s = 0; s < 8; ++s)
      A[s] = *(const h8*)(arow + s * 32);
    for (int T = wave; T < 9; T += 4) {
      f32x4 acc = {0.f, 0.f, 0.f, 0.f};
      const h8* bp = (const h8*)pack + (T * 8) * 64 + lane;
#pragma unroll
      for (int s = 0; s < 8; ++s)
        acc = __builtin_amdgcn_mfma_f32_16x16x32_f16(A[s], bp[s * 64], acc, 0, 0, 0);
      float bb = b12g[T * 16 + m];            // D col = lane&15
#pragma unroll
      for (int r = 0; r < 4; ++r)
        ew[(q * 4 + r) * EWP + T * 16 + m] = acc[r] + bb;   // D row = q*4+r = pixel
    }
  }
  __syncthreads();

  // ---- involution: thread=(p,g); 18x ds_read_b128, v_dot2_f32_f16 inner ----
  {
    const int p = t >> 4, g = t & 15;
    float ewr[9];
#pragma unroll
    for (int k = 0; k < 9; ++k) ewr[k] = ew[p * EWP + g * 9 + k];
    h2 wp[8];
#pragma unroll
    for (int m = 0; m < 8; ++m)
      wp[m] = pkrtz(ewr[m], ewr[m + 1]);
    const float w8 = ewr[8], wb0 = ewr[0];
    const int g144 = g * 144;
    const int pbase = p * XP;
    float res[16];
#pragma unroll
    for (int gc = 0; gc < 16; ++gc) res[gc] = 0.f;
#pragma unroll
    for (int j = 0; j < 18; ++j) {
      int f = g144 + j * 8;
      int tap = f >> 8;                     // constant within the 8-chunk
      int ch = f & 255;
      int di = (tap * 86) >> 8;             // tap/3
      int dj = tap - 3 * di;
      uint4 dv = *(const uint4*)(&xg[di * XR + (p + dj) * XP + ch]);
      h2 v[4];
      v[0] = __builtin_bit_cast(h2, dv.x);
      v[1] = __builtin_bit_cast(h2, dv.y);
      v[2] = __builtin_bit_cast(h2, dv.z);
      v[3] = __builtin_bit_cast(h2, dv.w);
#pragma unroll
      for (int i = 0; i < 4; ++i) {
        const int u = j * 8 + 2 * i;        // compile-time
        const int m = u % 9;
        if (m == 8) {                       // pair crosses gc boundary
          res[u / 9]     += (float)v[i][0] * w8;
          res[u / 9 + 1] += (float)v[i][1] * wb0;
        } else {
#if HAS_FDOT2
          res[u / 9] = __builtin_amdgcn_fdot2(v[i], wp[m], res[u / 9], false);
#else
          res[u / 9] += (float)v[i][0] * ewr[m] + (float)v[i][1] * ewr[m + 1];
#endif
        }
      }
    }
    float* orow = out + (size_t)(((((b << 6) + h) << 6) + w0 + p)) * 256 + (g << 4);
    *(float4*)(orow + 0)  = make_float4(res[0],  res[1],  res[2],  res[3]);
    *(float4*)(orow + 4)  = make_float4(res[4],  res[5],  res[6],  res[7]);
    *(float4*)(orow + 8)  = make_float4(res[8],  res[9],  res[10], res[11]);
    *(float4*)(orow + 12) = make_float4(res[12], res[13], res[14], res[15]);
  }
}
} // namespace

extern "C" void kernel_launch(void* const* d_in, const int* in_sizes, int n_in,
                              void* d_out, int out_size, void* d_ws, size_t ws_size,
                              hipStream_t stream) {
  const float* x  = (const float*)d_in[0];
  const float* W1 = (const float*)d_in[1];
  const float* b1 = (const float*)d_in[2];
  const float* W2 = (const float*)d_in[3];
  const float* b2 = (const float*)d_in[4];
  float* out = (float*)d_out;
  _Float16* pack = (_Float16*)d_ws;                        // 9*8*64*8 f16 = 73,728 B
  float* b12 = (float*)((char*)d_ws + 9 * 8 * 64 * 8 * 2);
  prep_w12<<<144, 256, 0, stream>>>(W1, b1, W2, b2, pack, b12);
  invo_fused<<<8 * 64 * 4, 256, 0, stream>>>(x, pack, b12, out);
}